// Round 1
// baseline (875.263 us; speedup 1.0000x reference)
//
#include <hip/hip_runtime.h>
#include <stdint.h>

#define KCB 196560   // codebook rows
#define DIM 24       // embed dim
#define BB  2        // batch
#define ZEL 12288    // B*D*16*16

// ---------- helpers ----------
__device__ __forceinline__ unsigned long long pack_key(float sim, int idx) {
  unsigned u = __float_as_uint(sim);
  u = (u & 0x80000000u) ? ~u : (u | 0x80000000u);       // order-preserving float->u32
  return ((unsigned long long)u << 32) | (unsigned)(~(unsigned)idx); // smaller idx wins ties
}

// ---------- init: residual = z, zero the whole output ----------
__global__ __launch_bounds__(256) void init_kernel(const float* __restrict__ z,
    float* __restrict__ residual, float* __restrict__ out, int outTotal) {
  int e = blockIdx.x * 256 + threadIdx.x;
  if (e < ZEL) residual[e] = z[e];
  if (e < outTotal) out[e] = 0.0f;
}

// ---------- downsample residual -> rdown tokens [B*n][24]; reset best ----------
__global__ __launch_bounds__(256) void down_kernel(const float* __restrict__ residual,
    float* __restrict__ rdown, unsigned long long* __restrict__ best, int t, int n) {
  int gid = blockIdx.x * 256 + threadIdx.x;
  if (gid < BB * n) best[gid] = 0ull;
  int total = BB * DIM * n;
  if (gid >= total) return;
  int sp = gid % n;
  int d  = (gid / n) % DIM;
  int b  = gid / (n * DIM);
  int oh = sp / t, ow = sp - oh * t;
  // jax.image.resize(bilinear, antialias=True): sample_f=(j+0.5)*in/out-0.5,
  // x=|sample_f-i|/kernel_scale, kernel_scale=max(in/out,1), triangle, normalize.
  float inv_scale = 16.0f / (float)t;
  float ks = inv_scale;                 // t<=16 so kernel_scale = 16/t
  float sf_h = ((float)oh + 0.5f) * inv_scale - 0.5f;
  float sf_w = ((float)ow + 0.5f) * inv_scale - 0.5f;
  float wh[16], ww[16];
  float sh = 0.f, sw = 0.f;
#pragma unroll
  for (int i = 0; i < 16; ++i) {
    float vh = fmaxf(0.f, 1.f - fabsf(sf_h - (float)i) / ks);
    wh[i] = vh; sh += vh;
    float vw = fmaxf(0.f, 1.f - fabsf(sf_w - (float)i) / ks);
    ww[i] = vw; sw += vw;
  }
#pragma unroll
  for (int i = 0; i < 16; ++i) { wh[i] /= sh; ww[i] /= sw; }
  const float* resb = residual + (b * DIM + d) * 256;
  float acc = 0.f;
  for (int ih = 0; ih < 16; ++ih) {
    float ra = 0.f;
#pragma unroll
    for (int iw = 0; iw < 16; ++iw) ra = fmaf(ww[iw], resb[ih * 16 + iw], ra);
    acc = fmaf(wh[ih], ra, acc);
  }
  rdown[(b * n + sp) * DIM + d] = acc;
}

// ---------- argmax over codebook ----------
// P = token replication width (pow2), R = 256/P row-split. Thread owns token
// tid%P (+j*256 slots when TPT=2), streams its row sub-chunk, keeps running max.
template<int P, int TPT>
__global__ __launch_bounds__(256) void argmax_kernel(const float* __restrict__ cb,
    const float* __restrict__ rdown, unsigned long long* __restrict__ best,
    int T, int rowsPerBlock) {
  __shared__ unsigned long long lb[256 * TPT];
  int tid = threadIdx.x;
#pragma unroll
  for (int j = 0; j < TPT; ++j) lb[tid + 256 * j] = 0ull;
  __syncthreads();
  int tok[TPT]; bool valid[TPT];
  float tv[TPT][DIM];
#pragma unroll
  for (int j = 0; j < TPT; ++j) {
    int t = (tid % P) + j * P;
    valid[j] = (t < T);
    tok[j] = valid[j] ? t : 0;
    const float4* tp = (const float4*)(rdown + tok[j] * DIM);
#pragma unroll
    for (int q = 0; q < 6; ++q) {
      float4 v = tp[q];
      tv[j][q*4+0] = v.x; tv[j][q*4+1] = v.y; tv[j][q*4+2] = v.z; tv[j][q*4+3] = v.w;
    }
  }
  float bs[TPT]; int bi[TPT];
#pragma unroll
  for (int j = 0; j < TPT; ++j) { bs[j] = -3.402823466e38f; bi[j] = 0; }
  const int R = 256 / P;
  int sub = tid / P;
  int base = blockIdx.x * rowsPerBlock;
  int rowEnd = min(KCB, base + rowsPerBlock);
  for (int r = base + sub; r < rowEnd; r += R) {
    const float4* cp = (const float4*)(cb + r * DIM);
    float c[DIM];
#pragma unroll
    for (int q = 0; q < 6; ++q) {
      float4 v = cp[q];
      c[q*4+0] = v.x; c[q*4+1] = v.y; c[q*4+2] = v.z; c[q*4+3] = v.w;
    }
#pragma unroll
    for (int j = 0; j < TPT; ++j) {
      float acc = 0.f;
#pragma unroll
      for (int k = 0; k < DIM; ++k) acc = fmaf(tv[j][k], c[k], acc);
      if (acc > bs[j]) { bs[j] = acc; bi[j] = r; }   // strict > keeps lowest idx
    }
  }
#pragma unroll
  for (int j = 0; j < TPT; ++j)
    if (valid[j]) atomicMax(&lb[tok[j]], pack_key(bs[j], bi[j]));
  __syncthreads();
#pragma unroll
  for (int j = 0; j < TPT; ++j) {
    int tt = tid + 256 * j;
    if (tt < T) atomicMax(&best[tt], lb[tt]);
  }
}

// ---------- gather zq, upsample, update z_hat & residual, write indices ----------
template<int TSZ>
__global__ __launch_bounds__(256) void update_kernel(const float* __restrict__ cb,
    const unsigned long long* __restrict__ best, float* __restrict__ residual,
    float* __restrict__ out, int idxBase) {
  constexpr int N = TSZ * TSZ;
  constexpr int T = BB * N;
  __shared__ float zq[T * DIM];
  int tid = threadIdx.x;
  for (int slot = tid; slot < T; slot += 256) {
    unsigned long long key = best[slot];
    int idx = (int)(~(unsigned)key);
    const float* cv = cb + (long long)idx * DIM;
    float v[DIM]; float ss = 0.f;
#pragma unroll
    for (int k = 0; k < DIM; ++k) { v[k] = cv[k]; ss = fmaf(v[k], v[k], ss); }
    float nrm = sqrtf(ss);                       // jnp.linalg.norm, then divide
#pragma unroll
    for (int k = 0; k < DIM; ++k) zq[slot * DIM + k] = v[k] / nrm;
    if (blockIdx.x == 0) out[idxBase + slot] = (float)idx;  // indices as f32
  }
  __syncthreads();
  int e = blockIdx.x * 256 + tid;                // 48 blocks cover 12288 exactly
  int w = e & 15, h = (e >> 4) & 15;
  int d = (e >> 8) % DIM;
  int b = e / (DIM * 256);
  // upsample t->16: scale>1 so kernel_scale=1 (plain bilinear + edge renorm)
  float inv_scale = (float)TSZ / 16.0f;
  float sf_h = ((float)h + 0.5f) * inv_scale - 0.5f;
  float sf_w = ((float)w + 0.5f) * inv_scale - 0.5f;
  float wh[TSZ], ww[TSZ];
  float sh = 0.f, sw = 0.f;
#pragma unroll
  for (int j = 0; j < TSZ; ++j) {
    float vh = fmaxf(0.f, 1.f - fabsf(sf_h - (float)j));
    wh[j] = vh; sh += vh;
    float vw = fmaxf(0.f, 1.f - fabsf(sf_w - (float)j));
    ww[j] = vw; sw += vw;
  }
#pragma unroll
  for (int j = 0; j < TSZ; ++j) { wh[j] /= sh; ww[j] /= sw; }
  const float* zb = zq + (b * N) * DIM + d;      // all lanes in block share (b,d): LDS broadcast
  float acc = 0.f;
#pragma unroll
  for (int th = 0; th < TSZ; ++th) {
    float ra = 0.f;
#pragma unroll
    for (int tw = 0; tw < TSZ; ++tw) ra = fmaf(ww[tw], zb[(th * TSZ + tw) * DIM], ra);
    acc = fmaf(wh[th], ra, acc);
  }
  out[e] += acc;
  residual[e] -= acc;
}

// ---------- host ----------
extern "C" void kernel_launch(void* const* d_in, const int* in_sizes, int n_in,
                              void* d_out, int out_size, void* d_ws, size_t ws_size,
                              hipStream_t stream) {
  const float* z  = (const float*)d_in[0];
  const float* cb = (const float*)d_in[1];
  float* out = (float*)d_out;
  float* residual = (float*)d_ws;                          // 12288 f
  float* rdown = residual + ZEL;                           // 12288 f (max 512 tok * 24)
  unsigned long long* best =
      (unsigned long long*)((char*)d_ws + 2 * ZEL * sizeof(float)); // 512 u64

  static const int TS[10] = {1, 2, 3, 4, 5, 6, 8, 10, 13, 16};

  init_kernel<<<(out_size + 255) / 256, 256, 0, stream>>>(z, residual, out, out_size);

  int prefix = 0;
  for (int s = 0; s < 10; ++s) {
    int t = TS[s], n = t * t, T = BB * n;
    int dtotal = BB * DIM * n;
    down_kernel<<<(dtotal + 255) / 256, 256, 0, stream>>>(residual, rdown, best, t, n);

    if (T <= 2)        argmax_kernel<2, 1><<<256, 256, 0, stream>>>(cb, rdown, best, T, 768);
    else if (T <= 8)   argmax_kernel<8, 1><<<256, 256, 0, stream>>>(cb, rdown, best, T, 768);
    else if (T <= 32)  argmax_kernel<32, 1><<<256, 256, 0, stream>>>(cb, rdown, best, T, 768);
    else if (T <= 64)  argmax_kernel<64, 1><<<256, 256, 0, stream>>>(cb, rdown, best, T, 768);
    else if (T <= 128) argmax_kernel<128, 1><<<256, 256, 0, stream>>>(cb, rdown, best, T, 768);
    else if (T <= 256) argmax_kernel<256, 1><<<1024, 256, 0, stream>>>(cb, rdown, best, T, 192);
    else               argmax_kernel<256, 2><<<1024, 256, 0, stream>>>(cb, rdown, best, T, 192);

    int idxBase = ZEL + BB * prefix;
    switch (t) {
      case 1:  update_kernel<1><<<48, 256, 0, stream>>>(cb, best, residual, out, idxBase); break;
      case 2:  update_kernel<2><<<48, 256, 0, stream>>>(cb, best, residual, out, idxBase); break;
      case 3:  update_kernel<3><<<48, 256, 0, stream>>>(cb, best, residual, out, idxBase); break;
      case 4:  update_kernel<4><<<48, 256, 0, stream>>>(cb, best, residual, out, idxBase); break;
      case 5:  update_kernel<5><<<48, 256, 0, stream>>>(cb, best, residual, out, idxBase); break;
      case 6:  update_kernel<6><<<48, 256, 0, stream>>>(cb, best, residual, out, idxBase); break;
      case 8:  update_kernel<8><<<48, 256, 0, stream>>>(cb, best, residual, out, idxBase); break;
      case 10: update_kernel<10><<<48, 256, 0, stream>>>(cb, best, residual, out, idxBase); break;
      case 13: update_kernel<13><<<48, 256, 0, stream>>>(cb, best, residual, out, idxBase); break;
      case 16: update_kernel<16><<<48, 256, 0, stream>>>(cb, best, residual, out, idxBase); break;
    }
    prefix += n;
  }
}

// Round 2
// 665.094 us; speedup vs baseline: 1.3160x; 1.3160x over previous
//
#include <hip/hip_runtime.h>
#include <stdint.h>

#define KCB 196560   // codebook rows
#define DIM 24       // embed dim
#define BB  2        // batch
#define ZEL 12288    // B*D*16*16

// ---------- helpers ----------
__device__ __forceinline__ unsigned long long pack_key(float sim, int idx) {
  unsigned u = __float_as_uint(sim);
  u = (u & 0x80000000u) ? ~u : (u | 0x80000000u);       // order-preserving float->u32
  return ((unsigned long long)u << 32) | (unsigned)(~(unsigned)idx); // smaller idx wins ties
}

// ---------- init: residual = z, zero the whole output ----------
__global__ __launch_bounds__(256) void init_kernel(const float* __restrict__ z,
    float* __restrict__ residual, float* __restrict__ out, int outTotal) {
  int e = blockIdx.x * 256 + threadIdx.x;
  if (e < ZEL) residual[e] = z[e];
  if (e < outTotal) out[e] = 0.0f;
}

// ---------- downsample residual -> rdown tokens [B*n][24]; reset best ----------
__global__ __launch_bounds__(256) void down_kernel(const float* __restrict__ residual,
    float* __restrict__ rdown, unsigned long long* __restrict__ best, int t, int n) {
  int gid = blockIdx.x * 256 + threadIdx.x;
  if (gid < BB * n) best[gid] = 0ull;
  int total = BB * DIM * n;
  if (gid >= total) return;
  int sp = gid % n;
  int d  = (gid / n) % DIM;
  int b  = gid / (n * DIM);
  int oh = sp / t, ow = sp - oh * t;
  float inv_scale = 16.0f / (float)t;
  float ks = inv_scale;
  float sf_h = ((float)oh + 0.5f) * inv_scale - 0.5f;
  float sf_w = ((float)ow + 0.5f) * inv_scale - 0.5f;
  float wh[16], ww[16];
  float sh = 0.f, sw = 0.f;
#pragma unroll
  for (int i = 0; i < 16; ++i) {
    float vh = fmaxf(0.f, 1.f - fabsf(sf_h - (float)i) / ks);
    wh[i] = vh; sh += vh;
    float vw = fmaxf(0.f, 1.f - fabsf(sf_w - (float)i) / ks);
    ww[i] = vw; sw += vw;
  }
#pragma unroll
  for (int i = 0; i < 16; ++i) { wh[i] /= sh; ww[i] /= sw; }
  const float* resb = residual + (b * DIM + d) * 256;
  float acc = 0.f;
  for (int ih = 0; ih < 16; ++ih) {
    float ra = 0.f;
#pragma unroll
    for (int iw = 0; iw < 16; ++iw) ra = fmaf(ww[iw], resb[ih * 16 + iw], ra);
    acc = fmaf(wh[ih], ra, acc);
  }
  rdown[(b * n + sp) * DIM + d] = acc;
}

// ---------- argmax over codebook ----------
// Rows are wave-uniform (blockIdx/wave-id/loop only) -> scalar s_load path.
// Lane owns tokens group*64*TPT + j*64 + lane (in VGPRs). Waves globally
// partition (token-group x row-slice); merge via packed-u64 atomicMax.
struct RowBuf { float4 q[6]; };

__device__ __forceinline__ void load_row(const float* __restrict__ cb, int r, RowBuf& b) {
  const float4* p = (const float4*)(cb + (size_t)r * DIM);
#pragma unroll
  for (int q = 0; q < 6; ++q) b.q[q] = p[q];
}

template<int TPT>
__global__ __launch_bounds__(256) void argmax_kernel(const float* __restrict__ cb,
    const float* __restrict__ rdown, unsigned long long* __restrict__ best,
    int T, int G, int rowsPerSlice) {
  __shared__ unsigned long long lb[512];
  int tid = threadIdx.x;
  lb[tid] = 0ull; lb[tid + 256] = 0ull;
  __syncthreads();
  int lane = tid & 63;
  int w = __builtin_amdgcn_readfirstlane(tid >> 6);   // wave-uniform wave id
  int gw = blockIdx.x * 4 + w;
  int group = gw % G;
  int slice = gw / G;
  int rBeg = slice * rowsPerSlice;
  int rEnd = min(KCB, rBeg + rowsPerSlice);

  int tok[TPT]; bool valid[TPT];
  float tv[TPT][DIM];
#pragma unroll
  for (int j = 0; j < TPT; ++j) {
    int t = group * (64 * TPT) + j * 64 + lane;
    valid[j] = (t < T);
    tok[j] = valid[j] ? t : 0;
    const float4* tp = (const float4*)(rdown + tok[j] * DIM);
#pragma unroll
    for (int q = 0; q < 6; ++q) {
      float4 v = tp[q];
      tv[j][q*4+0] = v.x; tv[j][q*4+1] = v.y; tv[j][q*4+2] = v.z; tv[j][q*4+3] = v.w;
    }
  }
  float bs[TPT]; int bi[TPT];
#pragma unroll
  for (int j = 0; j < TPT; ++j) { bs[j] = -3.402823466e38f; bi[j] = 0; }

  if (rBeg < rEnd) {
    auto computeRow = [&](const RowBuf& R_, int r) {
      const float* c = (const float*)&R_.q[0];
#pragma unroll
      for (int j = 0; j < TPT; ++j) {
        float acc = 0.f;
#pragma unroll
        for (int k = 0; k < DIM; ++k) acc = fmaf(tv[j][k], c[k], acc);  // same chain as R1 (bit-exact)
        if (acc > bs[j]) { bs[j] = acc; bi[j] = r; }   // strict > keeps lowest idx
      }
    };
    RowBuf A, B, C;
    int r = rBeg;
    load_row(cb, r, A);
    if (r + 1 < rEnd) load_row(cb, r + 1, B);
    if (r + 2 < rEnd) load_row(cb, r + 2, C);
    while (true) {
      computeRow(A, r);
      if (r + 3 < rEnd) load_row(cb, r + 3, A);
      if (++r >= rEnd) break;
      computeRow(B, r);
      if (r + 3 < rEnd) load_row(cb, r + 3, B);
      if (++r >= rEnd) break;
      computeRow(C, r);
      if (r + 3 < rEnd) load_row(cb, r + 3, C);
      if (++r >= rEnd) break;
    }
#pragma unroll
    for (int j = 0; j < TPT; ++j)
      if (valid[j]) atomicMax(&lb[tok[j]], pack_key(bs[j], bi[j]));
  }
  __syncthreads();
  for (int t = tid; t < T; t += 256)
    if (lb[t]) atomicMax(&best[t], lb[t]);
}

// ---------- gather zq, upsample, update z_hat & residual, write indices ----------
template<int TSZ>
__global__ __launch_bounds__(256) void update_kernel(const float* __restrict__ cb,
    const unsigned long long* __restrict__ best, float* __restrict__ residual,
    float* __restrict__ out, int idxBase) {
  constexpr int N = TSZ * TSZ;
  constexpr int T = BB * N;
  __shared__ float zq[T * DIM];
  int tid = threadIdx.x;
  for (int slot = tid; slot < T; slot += 256) {
    unsigned long long key = best[slot];
    int idx = (int)(~(unsigned)key);
    const float* cv = cb + (long long)idx * DIM;
    float v[DIM]; float ss = 0.f;
#pragma unroll
    for (int k = 0; k < DIM; ++k) { v[k] = cv[k]; ss = fmaf(v[k], v[k], ss); }
    float nrm = sqrtf(ss);
#pragma unroll
    for (int k = 0; k < DIM; ++k) zq[slot * DIM + k] = v[k] / nrm;
    if (blockIdx.x == 0) out[idxBase + slot] = (float)idx;
  }
  __syncthreads();
  int e = blockIdx.x * 256 + tid;
  int w = e & 15, h = (e >> 4) & 15;
  int d = (e >> 8) % DIM;
  int b = e / (DIM * 256);
  float inv_scale = (float)TSZ / 16.0f;
  float sf_h = ((float)h + 0.5f) * inv_scale - 0.5f;
  float sf_w = ((float)w + 0.5f) * inv_scale - 0.5f;
  float wh[TSZ], ww[TSZ];
  float sh = 0.f, sw = 0.f;
#pragma unroll
  for (int j = 0; j < TSZ; ++j) {
    float vh = fmaxf(0.f, 1.f - fabsf(sf_h - (float)j));
    wh[j] = vh; sh += vh;
    float vw = fmaxf(0.f, 1.f - fabsf(sf_w - (float)j));
    ww[j] = vw; sw += vw;
  }
#pragma unroll
  for (int j = 0; j < TSZ; ++j) { wh[j] /= sh; ww[j] /= sw; }
  const float* zb = zq + (b * N) * DIM + d;
  float acc = 0.f;
#pragma unroll
  for (int th = 0; th < TSZ; ++th) {
    float ra = 0.f;
#pragma unroll
    for (int tw = 0; tw < TSZ; ++tw) ra = fmaf(ww[tw], zb[(th * TSZ + tw) * DIM], ra);
    acc = fmaf(wh[th], ra, acc);
  }
  out[e] += acc;
  residual[e] -= acc;
}

// ---------- host ----------
extern "C" void kernel_launch(void* const* d_in, const int* in_sizes, int n_in,
                              void* d_out, int out_size, void* d_ws, size_t ws_size,
                              hipStream_t stream) {
  const float* z  = (const float*)d_in[0];
  const float* cb = (const float*)d_in[1];
  float* out = (float*)d_out;
  float* residual = (float*)d_ws;                          // 12288 f
  float* rdown = residual + ZEL;                           // 12288 f
  unsigned long long* best =
      (unsigned long long*)((char*)d_ws + 2 * ZEL * sizeof(float)); // 512 u64

  static const int TS[10] = {1, 2, 3, 4, 5, 6, 8, 10, 13, 16};

  init_kernel<<<(out_size + 255) / 256, 256, 0, stream>>>(z, residual, out, out_size);

  int prefix = 0;
  for (int s = 0; s < 10; ++s) {
    int t = TS[s], n = t * t, T = BB * n;
    int dtotal = BB * DIM * n;
    down_kernel<<<(dtotal + 255) / 256, 256, 0, stream>>>(residual, rdown, best, t, n);

    int TPT = (T > 256) ? 2 : 1;
    int G = (T + 64 * TPT - 1) / (64 * TPT);
    int grid = (T >= 128) ? 1024 : (T >= 32 ? 512 : 256);
    int numSlices = (grid * 4) / G;
    int rowsPerSlice = (KCB + numSlices - 1) / numSlices;
    if (TPT == 2)
      argmax_kernel<2><<<grid, 256, 0, stream>>>(cb, rdown, best, T, G, rowsPerSlice);
    else
      argmax_kernel<1><<<grid, 256, 0, stream>>>(cb, rdown, best, T, G, rowsPerSlice);

    int idxBase = ZEL + BB * prefix;
    switch (t) {
      case 1:  update_kernel<1><<<48, 256, 0, stream>>>(cb, best, residual, out, idxBase); break;
      case 2:  update_kernel<2><<<48, 256, 0, stream>>>(cb, best, residual, out, idxBase); break;
      case 3:  update_kernel<3><<<48, 256, 0, stream>>>(cb, best, residual, out, idxBase); break;
      case 4:  update_kernel<4><<<48, 256, 0, stream>>>(cb, best, residual, out, idxBase); break;
      case 5:  update_kernel<5><<<48, 256, 0, stream>>>(cb, best, residual, out, idxBase); break;
      case 6:  update_kernel<6><<<48, 256, 0, stream>>>(cb, best, residual, out, idxBase); break;
      case 8:  update_kernel<8><<<48, 256, 0, stream>>>(cb, best, residual, out, idxBase); break;
      case 10: update_kernel<10><<<48, 256, 0, stream>>>(cb, best, residual, out, idxBase); break;
      case 13: update_kernel<13><<<48, 256, 0, stream>>>(cb, best, residual, out, idxBase); break;
      case 16: update_kernel<16><<<48, 256, 0, stream>>>(cb, best, residual, out, idxBase); break;
    }
    prefix += n;
  }
}

// Round 5
// 469.032 us; speedup vs baseline: 1.8661x; 1.4180x over previous
//
#include <hip/hip_runtime.h>
#include <stdint.h>

#define KCB 196560   // codebook rows
#define DIM 24       // embed dim
#define BB  2        // batch
#define ZEL 12288    // B*D*16*16
#define AGRID 768    // argmax blocks
#define RPB 256      // codebook rows per block (768*256 = 196608 >= 196560)

__device__ __forceinline__ unsigned long long pack_key(float sim, int idx) {
  unsigned u = __float_as_uint(sim);
  u = (u & 0x80000000u) ? ~u : (u | 0x80000000u);       // order-preserving float->u32
  return ((unsigned long long)u << 32) | (unsigned)(~(unsigned)idx); // smaller idx wins ties
}

// ---------- init: residual = z, zero the whole output (R2 verbatim) ----------
__global__ __launch_bounds__(256) void init_kernel(const float* __restrict__ z,
    float* __restrict__ residual, float* __restrict__ out, int outTotal) {
  int e = blockIdx.x * 256 + threadIdx.x;
  if (e < ZEL) residual[e] = z[e];
  if (e < outTotal) out[e] = 0.0f;
}

// ---------- downsample residual -> rdown tokens; reset best (R2 verbatim) ----------
__global__ __launch_bounds__(256) void down_kernel(const float* __restrict__ residual,
    float* __restrict__ rdown, unsigned long long* __restrict__ best, int t, int n) {
  int gid = blockIdx.x * 256 + threadIdx.x;
  if (gid < BB * n) best[gid] = 0ull;
  int total = BB * DIM * n;
  if (gid >= total) return;
  int sp = gid % n;
  int d  = (gid / n) % DIM;
  int b  = gid / (n * DIM);
  int oh = sp / t, ow = sp - oh * t;
  float inv_scale = 16.0f / (float)t;
  float ks = inv_scale;
  float sf_h = ((float)oh + 0.5f) * inv_scale - 0.5f;
  float sf_w = ((float)ow + 0.5f) * inv_scale - 0.5f;
  float wh[16], ww[16];
  float sh = 0.f, sw = 0.f;
#pragma unroll
  for (int i = 0; i < 16; ++i) {
    float vh = fmaxf(0.f, 1.f - fabsf(sf_h - (float)i) / ks);
    wh[i] = vh; sh += vh;
    float vw = fmaxf(0.f, 1.f - fabsf(sf_w - (float)i) / ks);
    ww[i] = vw; sw += vw;
  }
#pragma unroll
  for (int i = 0; i < 16; ++i) { wh[i] /= sh; ww[i] /= sw; }
  const float* resb = residual + (b * DIM + d) * 256;
  float acc = 0.f;
  for (int ih = 0; ih < 16; ++ih) {
    float ra = 0.f;
#pragma unroll
    for (int iw = 0; iw < 16; ++iw) ra = fmaf(ww[iw], resb[ih * 16 + iw], ra);
    acc = fmaf(wh[ih], ra, acc);
  }
  rdown[(b * n + sp) * DIM + d] = acc;
}

// ---------- argmax: block stages RPB codebook rows in LDS, streams from LDS ----------
template<int C>
__device__ __forceinline__ void argmax_chunk(int cbase, int lane, int wBeg, int wEnd,
    int rowBase, const float* __restrict__ rdown, const float* cbT,
    unsigned long long* lb, int T) {
  int tok[C]; bool valid[C]; float tv[C][DIM];
#pragma unroll
  for (int j = 0; j < C; ++j) {
    int tt = cbase + j * 64 + lane;
    valid[j] = tt < T;
    tok[j] = valid[j] ? tt : 0;
    const float4* tp = (const float4*)(rdown + tok[j] * DIM);
#pragma unroll
    for (int q = 0; q < 6; ++q) {
      float4 v = tp[q];
      tv[j][q*4+0] = v.x; tv[j][q*4+1] = v.y; tv[j][q*4+2] = v.z; tv[j][q*4+3] = v.w;
    }
  }
  float bs[C]; int bi[C];
#pragma unroll
  for (int j = 0; j < C; ++j) { bs[j] = -3.402823466e38f; bi[j] = 0; }
  for (int r = wBeg; r < wEnd; ++r) {
    const float4* cp = (const float4*)(cbT + r * DIM);   // wave-uniform: LDS broadcast
    float c[DIM];
#pragma unroll
    for (int q = 0; q < 6; ++q) {
      float4 v = cp[q];
      c[q*4+0] = v.x; c[q*4+1] = v.y; c[q*4+2] = v.z; c[q*4+3] = v.w;
    }
    int gr = rowBase + r;
#pragma unroll
    for (int j = 0; j < C; ++j) {
      float acc = 0.f;
#pragma unroll
      for (int k = 0; k < DIM; ++k) acc = fmaf(tv[j][k], c[k], acc);  // exact R2 chain
      if (acc > bs[j]) { bs[j] = acc; bi[j] = gr; }   // strict > keeps lowest idx
    }
  }
#pragma unroll
  for (int j = 0; j < C; ++j)
    if (valid[j]) atomicMax(&lb[tok[j]], pack_key(bs[j], bi[j]));
}

__global__ __launch_bounds__(256) void argmax_kernel(const float* __restrict__ cb,
    const float* __restrict__ rdown, unsigned long long* __restrict__ bb, int T) {
  __shared__ float cbT[RPB * DIM];              // 24 KB codebook slice
  __shared__ unsigned long long lb[512];
  int tid = threadIdx.x, blk = blockIdx.x;
  int lane = tid & 63, wv = tid >> 6;
  int rowBase = blk * RPB;
  int rowsHere = min(KCB - rowBase, RPB);       // 256, last block 208
  {
    const float4* s4 = (const float4*)(cb + (size_t)rowBase * DIM);
    float4* d4 = (float4*)cbT;
    int n4 = rowsHere * 6;
    for (int i = tid; i < n4; i += 256) d4[i] = s4[i];
  }
  lb[tid] = 0ull; lb[tid + 256] = 0ull;
  __syncthreads();

  int per = (rowsHere + 3) >> 2;                // per-wave row subrange
  int wBeg = min(rowsHere, wv * per);
  int wEnd = min(rowsHere, wBeg + per);

  int cbase = 0;
  while (cbase < T) {
    int rem = T - cbase;
    int ctpt = rem > 128 ? 4 : (rem > 64 ? 2 : 1);
    if (ctpt == 4)      argmax_chunk<4>(cbase, lane, wBeg, wEnd, rowBase, rdown, cbT, lb, T);
    else if (ctpt == 2) argmax_chunk<2>(cbase, lane, wBeg, wEnd, rowBase, rdown, cbT, lb, T);
    else                argmax_chunk<1>(cbase, lane, wBeg, wEnd, rowBase, rdown, cbT, lb, T);
    cbase += 64 * ctpt;
  }
  __syncthreads();
  for (int t0 = tid; t0 < T; t0 += 256)
    if (lb[t0]) atomicMax(&bb[t0], lb[t0]);     // plain R2 merge
}

// ---------- update (R2 verbatim): gather zq, upsample, z_hat/residual, indices ----------
template<int TSZ>
__global__ __launch_bounds__(256) void update_kernel(const float* __restrict__ cb,
    const unsigned long long* __restrict__ best, float* __restrict__ residual,
    float* __restrict__ out, int idxBase) {
  constexpr int N = TSZ * TSZ;
  constexpr int T = BB * N;
  __shared__ float zq[T * DIM];
  int tid = threadIdx.x;
  for (int slot = tid; slot < T; slot += 256) {
    unsigned long long key = best[slot];
    int idx = (int)(~(unsigned)key);
    const float* cv = cb + (long long)idx * DIM;
    float v[DIM]; float ss = 0.f;
#pragma unroll
    for (int k = 0; k < DIM; ++k) { v[k] = cv[k]; ss = fmaf(v[k], v[k], ss); }
    float nrm = sqrtf(ss);
#pragma unroll
    for (int k = 0; k < DIM; ++k) zq[slot * DIM + k] = v[k] / nrm;
    if (blockIdx.x == 0) out[idxBase + slot] = (float)idx;
  }
  __syncthreads();
  int e = blockIdx.x * 256 + tid;
  int w = e & 15, h = (e >> 4) & 15;
  int d = (e >> 8) % DIM;
  int b = e / (DIM * 256);
  float inv_scale = (float)TSZ / 16.0f;
  float sf_h = ((float)h + 0.5f) * inv_scale - 0.5f;
  float sf_w = ((float)w + 0.5f) * inv_scale - 0.5f;
  float wh[TSZ], ww[TSZ];
  float sh = 0.f, sw = 0.f;
#pragma unroll
  for (int j = 0; j < TSZ; ++j) {
    float vh = fmaxf(0.f, 1.f - fabsf(sf_h - (float)j));
    wh[j] = vh; sh += vh;
    float vw = fmaxf(0.f, 1.f - fabsf(sf_w - (float)j));
    ww[j] = vw; sw += vw;
  }
#pragma unroll
  for (int j = 0; j < TSZ; ++j) { wh[j] /= sh; ww[j] /= sw; }
  const float* zb = zq + (b * N) * DIM + d;
  float acc = 0.f;
#pragma unroll
  for (int th = 0; th < TSZ; ++th) {
    float ra = 0.f;
#pragma unroll
    for (int tw = 0; tw < TSZ; ++tw) ra = fmaf(ww[tw], zb[(th * TSZ + tw) * DIM], ra);
    acc = fmaf(wh[th], ra, acc);
  }
  out[e] += acc;
  residual[e] -= acc;
}

// ---------- host (R2 verbatim structure, single 512-u64 best) ----------
extern "C" void kernel_launch(void* const* d_in, const int* in_sizes, int n_in,
                              void* d_out, int out_size, void* d_ws, size_t ws_size,
                              hipStream_t stream) {
  const float* z  = (const float*)d_in[0];
  const float* cb = (const float*)d_in[1];
  float* out = (float*)d_out;
  float* residual = (float*)d_ws;                          // 12288 f
  float* rdown = residual + ZEL;                           // 12288 f
  unsigned long long* best =
      (unsigned long long*)((char*)d_ws + 2 * ZEL * sizeof(float)); // 512 u64 (proven footprint)

  static const int TS[10] = {1, 2, 3, 4, 5, 6, 8, 10, 13, 16};

  init_kernel<<<(out_size + 255) / 256, 256, 0, stream>>>(z, residual, out, out_size);

  int prefix = 0;
  for (int s = 0; s < 10; ++s) {
    int t = TS[s], n = t * t, T = BB * n;
    int dtotal = BB * DIM * n;
    down_kernel<<<(dtotal + 255) / 256, 256, 0, stream>>>(residual, rdown, best, t, n);

    argmax_kernel<<<AGRID, 256, 0, stream>>>(cb, rdown, best, T);

    int idxBase = ZEL + BB * prefix;
    switch (t) {
      case 1:  update_kernel<1><<<48, 256, 0, stream>>>(cb, best, residual, out, idxBase); break;
      case 2:  update_kernel<2><<<48, 256, 0, stream>>>(cb, best, residual, out, idxBase); break;
      case 3:  update_kernel<3><<<48, 256, 0, stream>>>(cb, best, residual, out, idxBase); break;
      case 4:  update_kernel<4><<<48, 256, 0, stream>>>(cb, best, residual, out, idxBase); break;
      case 5:  update_kernel<5><<<48, 256, 0, stream>>>(cb, best, residual, out, idxBase); break;
      case 6:  update_kernel<6><<<48, 256, 0, stream>>>(cb, best, residual, out, idxBase); break;
      case 8:  update_kernel<8><<<48, 256, 0, stream>>>(cb, best, residual, out, idxBase); break;
      case 10: update_kernel<10><<<48, 256, 0, stream>>>(cb, best, residual, out, idxBase); break;
      case 13: update_kernel<13><<<48, 256, 0, stream>>>(cb, best, residual, out, idxBase); break;
      case 16: update_kernel<16><<<48, 256, 0, stream>>>(cb, best, residual, out, idxBase); break;
    }
    prefix += n;
  }
}